// Round 1
// baseline (3863.904 us; speedup 1.0000x reference)
//
#include <hip/hip_runtime.h>
#include <math.h>

#define Nn 32
#define Cc 256
#define Tt 64
#define Vv 25
#define Kk 3
#define Dd 256
#define KT 9
#define PADt 4
#define NBLK (Nn*Tt)          // 2048 (n,t) blocks
#define CNT_PER_CH 51200.0f   // N*T*V

// ---------------------------------------------------------------------------
// Kernel 1: GCN. y2[n,d,t,w] = sum_{k,c} Wg[k,d,c] * xa_k[c,w] + bias2[d,w]
//   xa_k[c,w] = sum_v x[n,c,t,v] * A[k,v,w]
//   bias2[d,w] = sum_k bg[k,d] * colsum_A[k,w]
// One block per (n,t). 256 threads: thread = (dq 0..63, wq 0..3),
// owns d in {4dq..4dq+3} and a w-quarter (7/6/6/6) -> 4 FMA per LDS read.
// ---------------------------------------------------------------------------
__global__ __launch_bounds__(256) void gcn_kernel(
    const float* __restrict__ x, const float* __restrict__ A,
    const float* __restrict__ Wg, const float* __restrict__ bg,
    float* __restrict__ y2)
{
    const int t = blockIdx.x, n = blockIdx.y;
    const int tid = threadIdx.x;
    const int dq = tid & 63, wq = tid >> 6;
    const int w0 = wq * 6 + (wq != 0);
    const int nw = 6 + (wq == 0);

    __shared__ float x_s[Cc * Vv];        // 25.6 KB
    __shared__ float A_s[Kk * Vv * Vv];   // 7.5 KB
    __shared__ float Acs[Kk * Vv];        // col-sums of A
    __shared__ float xa_s[Cc * Vv + 1];   // +1: tolerated OOB read lane

    for (int idx = tid; idx < Cc * Vv; idx += 256) {
        int c = idx / Vv, v = idx - c * Vv;
        x_s[idx] = x[((n * Cc + c) * Tt + t) * Vv + v];
    }
    for (int idx = tid; idx < Kk * Vv * Vv; idx += 256) A_s[idx] = A[idx];
    if (tid < Kk * Vv) {
        int k = tid / Vv, w = tid - k * Vv;
        float s = 0.f;
        for (int v = 0; v < Vv; ++v) s += A[(k * Vv + v) * Vv + w];
        Acs[tid] = s;
    }
    __syncthreads();

    float acc[4][7];
    #pragma unroll
    for (int g = 0; g < 4; ++g) {
        int d = dq * 4 + g;
        float b0 = bg[0 * Dd + d], b1 = bg[1 * Dd + d], b2 = bg[2 * Dd + d];
        #pragma unroll
        for (int j = 0; j < 7; ++j) {
            int w = w0 + j;
            int wc = (w < Vv) ? w : (Vv - 1);   // clamp; lane unused when OOB
            acc[g][j] = b0 * Acs[0 * Vv + wc] + b1 * Acs[1 * Vv + wc] + b2 * Acs[2 * Vv + wc];
        }
    }

    for (int k = 0; k < Kk; ++k) {
        if (k) __syncthreads();
        // xa for this partition k
        for (int idx = tid; idx < Cc * Vv; idx += 256) {
            int c = idx / Vv, w = idx - c * Vv;
            float s = 0.f;
            #pragma unroll
            for (int v = 0; v < Vv; ++v)
                s += x_s[c * Vv + v] * A_s[(k * Vv + v) * Vv + w];
            xa_s[idx] = s;
        }
        __syncthreads();

        #pragma unroll 2
        for (int c4 = 0; c4 < Cc / 4; ++c4) {
            float wj[4][4];
            #pragma unroll
            for (int g = 0; g < 4; ++g) {
                const float4 wv = *reinterpret_cast<const float4*>(
                    Wg + (size_t)(k * Dd + dq * 4 + g) * Cc + c4 * 4);
                wj[g][0] = wv.x; wj[g][1] = wv.y; wj[g][2] = wv.z; wj[g][3] = wv.w;
            }
            #pragma unroll
            for (int j = 0; j < 4; ++j) {
                const int c = c4 * 4 + j;
                #pragma unroll
                for (int vvi = 0; vvi < 7; ++vvi) {
                    const float xv = xa_s[c * Vv + w0 + vvi];  // wave-uniform broadcast
                    acc[0][vvi] += wj[0][j] * xv;
                    acc[1][vvi] += wj[1][j] * xv;
                    acc[2][vvi] += wj[2][j] * xv;
                    acc[3][vvi] += wj[3][j] * xv;
                }
            }
        }
    }

    #pragma unroll
    for (int g = 0; g < 4; ++g) {
        int d = dq * 4 + g;
        float* dst = y2 + ((size_t)(n * Dd + d) * Tt + t) * Vv;
        for (int j = 0; j < nw; ++j) dst[w0 + j] = acc[g][j];
    }
}

// ---------------------------------------------------------------------------
// Kernel 2: TCN (9,1) conv + bias; writes z to d_out and per-block BN partials.
// z[n,d,t,v] = bt[d] + sum_{c,dt} Wt[d,c,dt] * y2[n,c,t+dt-4,v]
// One block per (n,t). LDS stages y2[c0:c0+64, t-4..t+4, :] (57.6 KB), 4 chunks.
// Thread = (dq, vq): 4 d's x a v-quarter -> 4 FMA per LDS read.
// ---------------------------------------------------------------------------
__global__ __launch_bounds__(256) void tcn_kernel(
    const float* __restrict__ y2, const float* __restrict__ Wt,
    const float* __restrict__ bt, float* __restrict__ z,
    float* __restrict__ psum, float* __restrict__ psq)
{
    const int t = blockIdx.x, n = blockIdx.y;
    const int bid = blockIdx.y * gridDim.x + blockIdx.x;
    const int tid = threadIdx.x;
    const int dq = tid & 63, vq = tid >> 6;
    const int v0 = vq * 6 + (vq != 0);
    const int nv = 6 + (vq == 0);

    __shared__ float ys[64 * KT * Vv + 1];   // 14401 floats, 57.6 KB

    float acc[4][7];
    #pragma unroll
    for (int g = 0; g < 4; ++g)
        #pragma unroll
        for (int j = 0; j < 7; ++j) acc[g][j] = 0.f;

    for (int ch = 0; ch < 4; ++ch) {
        __syncthreads();
        for (int idx = tid; idx < 64 * KT * Vv; idx += 256) {
            int cl = idx / (KT * Vv);
            int r = idx - cl * (KT * Vv);
            int tr = r / Vv, v = r - tr * Vv;
            int tt = t - PADt + tr;
            int c = ch * 64 + cl;
            ys[idx] = (tt >= 0 && tt < Tt)
                          ? y2[((size_t)(n * Cc + c) * Tt + tt) * Vv + v]
                          : 0.f;
        }
        __syncthreads();

        const float4* wp0 = reinterpret_cast<const float4*>(Wt + ((size_t)(dq * 4 + 0) * Dd + ch * 64) * KT);
        const float4* wp1 = reinterpret_cast<const float4*>(Wt + ((size_t)(dq * 4 + 1) * Dd + ch * 64) * KT);
        const float4* wp2 = reinterpret_cast<const float4*>(Wt + ((size_t)(dq * 4 + 2) * Dd + ch * 64) * KT);
        const float4* wp3 = reinterpret_cast<const float4*>(Wt + ((size_t)(dq * 4 + 3) * Dd + ch * 64) * KT);

        #pragma unroll 2
        for (int i4 = 0; i4 < 144; ++i4) {     // 576 (c,dt) scalars as float4
            float4 a0 = wp0[i4], a1 = wp1[i4], a2 = wp2[i4], a3 = wp3[i4];
            float wj[4][4] = {{a0.x, a0.y, a0.z, a0.w},
                              {a1.x, a1.y, a1.z, a1.w},
                              {a2.x, a2.y, a2.z, a2.w},
                              {a3.x, a3.y, a3.z, a3.w}};
            #pragma unroll
            for (int j = 0; j < 4; ++j) {
                const int cdt = i4 * 4 + j;          // = c_l*9 + dt; LDS base = cdt*25
                #pragma unroll
                for (int vvi = 0; vvi < 7; ++vvi) {
                    const float xv = ys[cdt * Vv + v0 + vvi];  // wave-uniform broadcast
                    acc[0][vvi] += wj[0][j] * xv;
                    acc[1][vvi] += wj[1][j] * xv;
                    acc[2][vvi] += wj[2][j] * xv;
                    acc[3][vvi] += wj[3][j] * xv;
                }
            }
        }
    }

    // epilogue: bias, store z, deterministic BN partials via LDS reduction
    __syncthreads();
    float* red = ys;   // reuse: [2][4][256] = 2048 floats
    #pragma unroll
    for (int g = 0; g < 4; ++g) {
        const int d = dq * 4 + g;
        const float bb = bt[d];
        float s = 0.f, q = 0.f;
        float* dst = z + ((size_t)(n * Dd + d) * Tt + t) * Vv;
        for (int j = 0; j < nv; ++j) {
            float zz = acc[g][j] + bb;
            dst[v0 + j] = zz;
            s += zz;
            q += zz * zz;
        }
        red[vq * 256 + d] = s;
        red[1024 + vq * 256 + d] = q;
    }
    __syncthreads();
    {
        const int d = tid;
        float s = red[d] + red[256 + d] + red[512 + d] + red[768 + d];
        float q = red[1024 + d] + red[1280 + d] + red[1536 + d] + red[1792 + d];
        psum[(size_t)d * NBLK + bid] = s;
        psq[(size_t)d * NBLK + bid] = q;
    }
}

// ---------------------------------------------------------------------------
// Kernel 3: reduce partials -> per-channel scale/shift
// ---------------------------------------------------------------------------
__global__ __launch_bounds__(256) void bn_stats_kernel(
    const float* __restrict__ psum, const float* __restrict__ psq,
    const float* __restrict__ gamma, const float* __restrict__ beta,
    float* __restrict__ scale, float* __restrict__ shift)
{
    const int d = blockIdx.x, tid = threadIdx.x;
    float s = 0.f, q = 0.f;
    for (int i = tid; i < NBLK; i += 256) {
        s += psum[(size_t)d * NBLK + i];
        q += psq[(size_t)d * NBLK + i];
    }
    #pragma unroll
    for (int off = 32; off; off >>= 1) {
        s += __shfl_down(s, off);
        q += __shfl_down(q, off);
    }
    __shared__ float rs[4], rq[4];
    const int wid = tid >> 6;
    if ((tid & 63) == 0) { rs[wid] = s; rq[wid] = q; }
    __syncthreads();
    if (tid == 0) {
        s = rs[0] + rs[1] + rs[2] + rs[3];
        q = rq[0] + rq[1] + rq[2] + rq[3];
        const float invN = 1.0f / CNT_PER_CH;
        float mean = s * invN;
        float var = q * invN - mean * mean;
        float inv = rsqrtf(var + 1e-5f);
        float g = gamma[d];
        scale[d] = g * inv;
        shift[d] = beta[d] - g * inv * mean;
    }
}

// ---------------------------------------------------------------------------
// Kernel 4: out = relu(z*scale[d] + shift[d] + x), in-place on d_out
// ---------------------------------------------------------------------------
__global__ __launch_bounds__(256) void bn_apply_kernel(
    const float* __restrict__ x, const float* __restrict__ scale,
    const float* __restrict__ shift, float* __restrict__ zo)
{
    const int total4 = (Nn * Dd * Tt * Vv) / 4;
    for (int i4 = blockIdx.x * 256 + threadIdx.x; i4 < total4; i4 += gridDim.x * 256) {
        const int i = i4 * 4;
        const int d = (i / (Tt * Vv)) & (Dd - 1);   // T*V=1600 divisible by 4 -> d uniform in vec
        float4 zv = reinterpret_cast<const float4*>(zo)[i4];
        float4 xv = reinterpret_cast<const float4*>(x)[i4];
        const float sc = scale[d], sh = shift[d];
        float4 r;
        r.x = fmaxf(zv.x * sc + sh + xv.x, 0.f);
        r.y = fmaxf(zv.y * sc + sh + xv.y, 0.f);
        r.z = fmaxf(zv.z * sc + sh + xv.z, 0.f);
        r.w = fmaxf(zv.w * sc + sh + xv.w, 0.f);
        reinterpret_cast<float4*>(zo)[i4] = r;
    }
}

extern "C" void kernel_launch(void* const* d_in, const int* in_sizes, int n_in,
                              void* d_out, int out_size, void* d_ws, size_t ws_size,
                              hipStream_t stream)
{
    const float* x     = (const float*)d_in[0];
    const float* A     = (const float*)d_in[1];
    const float* Wg    = (const float*)d_in[2];
    const float* bg    = (const float*)d_in[3];
    const float* Wt    = (const float*)d_in[4];
    const float* bt    = (const float*)d_in[5];
    const float* gamma = (const float*)d_in[6];
    const float* beta  = (const float*)d_in[7];
    float* out = (float*)d_out;

    float* y2    = (float*)d_ws;                        // 13,107,200 f
    float* psum  = y2 + (size_t)Nn * Dd * Tt * Vv;      // 524,288 f
    float* psq   = psum + (size_t)Dd * NBLK;            // 524,288 f
    float* scale = psq + (size_t)Dd * NBLK;             // 256 f
    float* shift = scale + Dd;                          // 256 f

    dim3 grid(Tt, Nn), block(256);
    gcn_kernel<<<grid, block, 0, stream>>>(x, A, Wg, bg, y2);
    tcn_kernel<<<grid, block, 0, stream>>>(y2, Wt, bt, out, psum, psq);
    bn_stats_kernel<<<Dd, 256, 0, stream>>>(psum, psq, gamma, beta, scale, shift);
    bn_apply_kernel<<<2048, 256, 0, stream>>>(x, scale, shift, out);
}

// Round 2
// 206.250 us; speedup vs baseline: 18.7340x; 18.7340x over previous
//
#include <hip/hip_runtime.h>
#include <math.h>

typedef unsigned short u16;
typedef short v8s __attribute__((ext_vector_type(8)));
typedef float v4f __attribute__((ext_vector_type(4)));

#define AS1 __attribute__((address_space(1)))
#define AS3 __attribute__((address_space(3)))

__device__ __forceinline__ float bf2f(u16 u) {
    union { unsigned int i; float f; } c; c.i = ((unsigned int)u) << 16; return c.f;
}
__device__ __forceinline__ u16 f2bf(float f) {
    union { float f; unsigned int i; } c; c.f = f;
    unsigned int u = c.i;
    return (u16)((u + 0x7FFFu + ((u >> 16) & 1u)) >> 16);
}
// async global->LDS, 16B per lane. LDS dest = base + lane*16 (wave-uniform base).
__device__ __forceinline__ void gload_lds16(const void* g, void* l) {
    __builtin_amdgcn_global_load_lds((const AS1 void*)(uintptr_t)g,
                                     (AS3 void*)(unsigned int)(uintptr_t)l,
                                     16, 0, 0);
}

#define Nn 32
#define Tt 64
#define Vv 25
#define NP 51200        // N*T*V positions
#define NBLK 400        // GEMM p-tiles (51200/128)

// ---------------------------------------------------------------------------
// prep: bf16 weight transposes + bias2[w][d] + zero pad
// Wgb[d][k*256+c] = Wg[k][d][c]   (768 per row)
// Wtb[d][dt*256+c] = Wt[d][c][dt] (2304 per row)
// bias2[w][d] = sum_k bg[k][d] * sum_v A[k][v][w]
// ---------------------------------------------------------------------------
__global__ __launch_bounds__(256) void prep_kernel(
    const float* __restrict__ Wg, const float* __restrict__ Wt,
    const float* __restrict__ A, const float* __restrict__ bg,
    u16* __restrict__ Wgb, u16* __restrict__ Wtb,
    float* __restrict__ bias2, float* __restrict__ zpad)
{
    const int idx = blockIdx.x * 256 + threadIdx.x;
    const int stride = gridDim.x * 256;
    for (int i = idx; i < 256 * 2304; i += stride) {
        int d = i / 2304, r = i - d * 2304, dt = r >> 8, c = r & 255;
        Wtb[i] = f2bf(Wt[(d * 256 + c) * 9 + dt]);
    }
    for (int i = idx; i < 256 * 768; i += stride) {
        int d = i / 768, r = i - d * 768, k = r >> 8, c = r & 255;
        Wgb[i] = f2bf(Wg[(k * 256 + d) * 256 + c]);
    }
    for (int i = idx; i < 25 * 256; i += stride) {
        int w = i >> 8, d = i & 255;
        float s = 0.f;
        for (int k = 0; k < 3; ++k) {
            float cs = 0.f;
            for (int v = 0; v < 25; ++v) cs += A[(k * 25 + v) * 25 + w];
            s += bg[k * 256 + d] * cs;
        }
        bias2[i] = s;
    }
    for (int i = idx; i < 256; i += stride) zpad[i] = 0.f;
}

// ---------------------------------------------------------------------------
// xa2[p=(n,t,w)][k*256+c] = sum_v x[n,c,t,v] * A[k,v,w]   (bf16 out)
// ---------------------------------------------------------------------------
__global__ __launch_bounds__(256) void xa_kernel(
    const float* __restrict__ x, const float* __restrict__ A,
    u16* __restrict__ xa2)
{
    const int t = blockIdx.x, n = blockIdx.y;
    const int tid = threadIdx.x;
    __shared__ float xs[256 * 25];     // x[n,:,t,:]
    __shared__ float As[3 * 625];
    for (int i = tid; i < 6400; i += 256) {
        int c = i / 25, v = i - c * 25;
        xs[i] = x[((n * 256 + c) * 64 + t) * 25 + v];
    }
    for (int i = tid; i < 1875; i += 256) As[i] = A[i];
    __syncthreads();
    const size_t pbase = ((size_t)n * 64 + t) * 25;
    for (int i = tid; i < 25 * 768; i += 256) {
        int w = i / 768, kc = i - w * 768;
        int k = kc >> 8, c = kc & 255;
        float s = 0.f;
        #pragma unroll
        for (int v = 0; v < 25; ++v) s += xs[c * 25 + v] * As[k * 625 + v * 25 + w];
        xa2[(pbase + w) * 768 + kc] = f2bf(s);
    }
}

// ---------------------------------------------------------------------------
// GEMM: C[p][d] = sum_k Ad[p][k] * Bw_rowd[d][k], M-tile 128, N=256, BK=64.
// 8 waves (2M x 4N), per-wave 64x64 out = 4x4 frags of 16x16x32 bf16 MFMA.
// LDS: A 16KB + B 32KB, linear rows of 128B; XOR-swizzle (16B granule) applied
// on the GLOBAL source (stage) and on ds_read addr (both-sides, rule 21).
// TCN=true: Ad rows shift by (dt-4)*25 positions with zero-pad at t edges;
//           epilogue emits bf16 z + per-block BN partials.
// ---------------------------------------------------------------------------
template<int KTOT, bool TCN>
__global__ __launch_bounds__(512, 2) void gemm_kernel(
    const u16* __restrict__ Ad, const u16* __restrict__ Bw,
    const float* __restrict__ bias, u16* __restrict__ outB,
    float* __restrict__ psum, float* __restrict__ psq,
    const u16* __restrict__ zpad)
{
    __shared__ u16 smem[24576];          // 48 KB
    u16* As = smem;                      // [128 rows][64 k] (swizzled)
    u16* Bs = smem + 8192;               // [256 rows][64 k] (swizzled)

    const int tid = threadIdx.x;
    const int wid = tid >> 6, lane = tid & 63;
    const int lr = lane & 15, hk = lane >> 4;
    const int wm = wid >> 2, wn = wid & 3;
    const int blk = blockIdx.x;
    const int rA = lane >> 3, sA = lane & 7;

    v4f acc[4][4];
    const v4f vzero = {0.f, 0.f, 0.f, 0.f};
    #pragma unroll
    for (int mf = 0; mf < 4; ++mf)
        #pragma unroll
        for (int nf = 0; nf < 4; ++nf) acc[mf][nf] = vzero;

    for (int kt = 0; kt < KTOT / 64; ++kt) {
        // ---- stage A: 16 chunks of 1KB (8 rows x 128B); wave does 2 ----
        #pragma unroll
        for (int i = 0; i < 2; ++i) {
            const int ch = wid + i * 8;
            const int row = ch * 8 + rA;
            const int p = blk * 128 + row;
            const int ss = sA ^ (row & 7);          // inverse-swizzled source slot
            const u16* src;
            if (TCN) {
                const int dt = kt >> 2, c0 = (kt & 3) << 6;
                const int tv = p % 1600, t = tv / 25;
                const int tp = t + dt - 4;
                const int p2 = p + (dt - 4) * 25;
                src = ((unsigned)tp < 64u) ? (Ad + (size_t)p2 * 256 + c0 + ss * 8) : zpad;
            } else {
                src = Ad + (size_t)p * 768 + kt * 64 + ss * 8;
            }
            gload_lds16(src, (char*)As + ch * 1024);
        }
        // ---- stage B: 32 chunks; wave does 4 ----
        #pragma unroll
        for (int i = 0; i < 4; ++i) {
            const int ch = wid + i * 8;
            const int d = ch * 8 + rA;
            const int ss = sA ^ (d & 7);
            gload_lds16(Bw + (size_t)d * KTOT + kt * 64 + ss * 8, (char*)Bs + ch * 1024);
        }
        __syncthreads();   // drains vmcnt: staged data visible

        v8s a[4][2], b[4][2];
        #pragma unroll
        for (int mf = 0; mf < 4; ++mf)
            #pragma unroll
            for (int kk = 0; kk < 2; ++kk) {
                const int row = wm * 64 + mf * 16 + lr;
                const int slot = kk * 4 + hk;
                a[mf][kk] = *(const v8s*)((const char*)As + row * 128 + ((slot ^ (row & 7)) << 4));
            }
        #pragma unroll
        for (int nf = 0; nf < 4; ++nf)
            #pragma unroll
            for (int kk = 0; kk < 2; ++kk) {
                const int row = wn * 64 + nf * 16 + lr;
                const int slot = kk * 4 + hk;
                b[nf][kk] = *(const v8s*)((const char*)Bs + row * 128 + ((slot ^ (row & 7)) << 4));
            }
        #pragma unroll
        for (int kk = 0; kk < 2; ++kk)
            #pragma unroll
            for (int mf = 0; mf < 4; ++mf)
                #pragma unroll
                for (int nf = 0; nf < 4; ++nf)
                    acc[mf][nf] = __builtin_amdgcn_mfma_f32_16x16x32_bf16(
                        a[mf][kk], b[nf][kk], acc[mf][nf], 0, 0, 0);
        __syncthreads();   // protect LDS from next stage
    }

    // ---- epilogue ----
    if (!TCN) {
        // y2T[p][d] = acc + bias2[p%25][d]
        #pragma unroll
        for (int mf = 0; mf < 4; ++mf) {
            #pragma unroll
            for (int j = 0; j < 4; ++j) {
                const int p = blk * 128 + wm * 64 + mf * 16 + hk * 4 + j;
                const int w = p % 25;
                #pragma unroll
                for (int nf = 0; nf < 4; ++nf) {
                    const int d = wn * 64 + nf * 16 + lr;
                    outB[(size_t)p * 256 + d] = f2bf(acc[mf][nf][j] + bias[w * 256 + d]);
                }
            }
        }
    } else {
        float s[4], q[4];
        #pragma unroll
        for (int nf = 0; nf < 4; ++nf) {
            const int d = wn * 64 + nf * 16 + lr;
            const float bb = bias[d];
            s[nf] = 0.f; q[nf] = 0.f;
            #pragma unroll
            for (int mf = 0; mf < 4; ++mf) {
                #pragma unroll
                for (int j = 0; j < 4; ++j) {
                    const int p = blk * 128 + wm * 64 + mf * 16 + hk * 4 + j;
                    const float zz = acc[mf][nf][j] + bb;
                    outB[(size_t)p * 256 + d] = f2bf(zz);
                    s[nf] += zz; q[nf] += zz * zz;
                }
            }
            s[nf] += __shfl_xor(s[nf], 16); s[nf] += __shfl_xor(s[nf], 32);
            q[nf] += __shfl_xor(q[nf], 16); q[nf] += __shfl_xor(q[nf], 32);
        }
        __syncthreads();
        float* red = (float*)smem;     // [2][256] sums, [2][256] sq
        if (hk == 0) {
            #pragma unroll
            for (int nf = 0; nf < 4; ++nf) {
                const int d = wn * 64 + nf * 16 + lr;
                red[wm * 256 + d] = s[nf];
                red[512 + wm * 256 + d] = q[nf];
            }
        }
        __syncthreads();
        if (tid < 256) {
            psum[(size_t)tid * NBLK + blk] = red[tid] + red[256 + tid];
            psq[(size_t)tid * NBLK + blk]  = red[512 + tid] + red[768 + tid];
        }
    }
}

// ---------------------------------------------------------------------------
// BN stats: reduce 400 block-partials per channel -> scale/shift
// ---------------------------------------------------------------------------
__global__ __launch_bounds__(256) void bn_stats_kernel(
    const float* __restrict__ psum, const float* __restrict__ psq,
    const float* __restrict__ gamma, const float* __restrict__ beta,
    float* __restrict__ scale, float* __restrict__ shift)
{
    const int d = blockIdx.x, tid = threadIdx.x;
    float s = 0.f, q = 0.f;
    for (int i = tid; i < NBLK; i += 256) {
        s += psum[(size_t)d * NBLK + i];
        q += psq[(size_t)d * NBLK + i];
    }
    #pragma unroll
    for (int off = 32; off; off >>= 1) {
        s += __shfl_down(s, off);
        q += __shfl_down(q, off);
    }
    __shared__ float rs[4], rq[4];
    if ((tid & 63) == 0) { rs[tid >> 6] = s; rq[tid >> 6] = q; }
    __syncthreads();
    if (tid == 0) {
        s = rs[0] + rs[1] + rs[2] + rs[3];
        q = rq[0] + rq[1] + rq[2] + rq[3];
        const float mean = s / 51200.f;
        const float var = q / 51200.f - mean * mean;
        const float inv = rsqrtf(var + 1e-5f);
        scale[d] = gamma[d] * inv;
        shift[d] = beta[d] - gamma[d] * inv * mean;
    }
}

// ---------------------------------------------------------------------------
// out[n,d,tv] = relu(z[p][d]*scale[d]+shift[d] + x[n,d,tv]); LDS transpose.
// Two half-D passes to keep LDS under 64KB. Block = (chunk of 64 tv, n).
// ---------------------------------------------------------------------------
__global__ __launch_bounds__(256) void bn_apply_kernel(
    const u16* __restrict__ zb, const float* __restrict__ x,
    const float* __restrict__ scale, const float* __restrict__ shift,
    float* __restrict__ out)
{
    const int chunk = blockIdx.x;   // 0..24
    const int n = blockIdx.y;       // 0..31
    const int tid = threadIdx.x;
    __shared__ u16 zs[128 * 66];    // 16.9 KB, padded rows
    const size_t p0 = (size_t)n * 1600 + chunk * 64;

    for (int half = 0; half < 2; ++half) {
        const int d0 = half * 128;
        if (half) __syncthreads();
        for (int i = tid; i < 128 * 64; i += 256) {
            const int pl = i >> 7, dl = i & 127;
            zs[dl * 66 + pl] = zb[(p0 + pl) * 256 + d0 + dl];
        }
        __syncthreads();
        for (int i = tid; i < 128 * 64; i += 256) {
            const int dl = i >> 6, j = i & 63;
            const int d = d0 + dl;
            const size_t addr = ((size_t)n * 256 + d) * 1600 + chunk * 64 + j;
            const float r = bf2f(zs[dl * 66 + j]) * scale[d] + shift[d] + x[addr];
            out[addr] = fmaxf(r, 0.f);
        }
    }
}

extern "C" void kernel_launch(void* const* d_in, const int* in_sizes, int n_in,
                              void* d_out, int out_size, void* d_ws, size_t ws_size,
                              hipStream_t stream)
{
    const float* x     = (const float*)d_in[0];
    const float* A     = (const float*)d_in[1];
    const float* Wg    = (const float*)d_in[2];
    const float* bg    = (const float*)d_in[3];
    const float* Wt    = (const float*)d_in[4];
    const float* bt    = (const float*)d_in[5];
    const float* gamma = (const float*)d_in[6];
    const float* beta  = (const float*)d_in[7];
    float* out = (float*)d_out;

    char* w = (char*)d_ws;
    u16*   xa2   = (u16*)(w);                    // 78,643,200 B
    u16*   y2T   = (u16*)(w + 78643200);         // 26,214,400 B
    u16*   zb    = (u16*)(w + 104857600);        // 26,214,400 B
    u16*   Wgb   = (u16*)(w + 131072000);        //    393,216 B
    u16*   Wtb   = (u16*)(w + 131465216);        //  1,179,648 B
    float* bias2 = (float*)(w + 132644864);      //     25,600 B
    float* psum  = (float*)(w + 132670464);      //    409,600 B
    float* psq   = (float*)(w + 133080064);      //    409,600 B
    float* scale = (float*)(w + 133489664);      //      1,024 B
    float* shift = (float*)(w + 133490688);      //      1,024 B
    float* zpad  = (float*)(w + 133491712);      //      1,024 B (zeroed)

    prep_kernel<<<512, 256, 0, stream>>>(Wg, Wt, A, bg, Wgb, Wtb, bias2, zpad);
    xa_kernel<<<dim3(64, 32), 256, 0, stream>>>(x, A, xa2);
    gemm_kernel<768, false><<<NBLK, 512, 0, stream>>>(xa2, Wgb, bias2, y2T,
                                                      nullptr, nullptr, (const u16*)zpad);
    gemm_kernel<2304, true><<<NBLK, 512, 0, stream>>>(y2T, Wtb, bt, zb,
                                                      psum, psq, (const u16*)zpad);
    bn_stats_kernel<<<256, 256, 0, stream>>>(psum, psq, gamma, beta, scale, shift);
    bn_apply_kernel<<<dim3(25, 32), 256, 0, stream>>>(zb, x, scale, shift, out);
}

// Round 3
// 169.768 us; speedup vs baseline: 22.7599x; 1.2149x over previous
//
#include <hip/hip_runtime.h>
#include <math.h>

typedef unsigned short u16;
typedef short v8s __attribute__((ext_vector_type(8)));
typedef float v4f __attribute__((ext_vector_type(4)));

#define AS1 __attribute__((address_space(1)))
#define AS3 __attribute__((address_space(3)))

__device__ __forceinline__ float bf2f(u16 u) {
    union { unsigned int i; float f; } c; c.i = ((unsigned int)u) << 16; return c.f;
}
__device__ __forceinline__ u16 f2bf(float f) {
    union { float f; unsigned int i; } c; c.f = f;
    unsigned int u = c.i;
    return (u16)((u + 0x7FFFu + ((u >> 16) & 1u)) >> 16);
}
// async global->LDS, 16B per lane. LDS dest = base + lane*16 (wave-uniform base).
__device__ __forceinline__ void gload_lds16(const void* g, void* l) {
    __builtin_amdgcn_global_load_lds((const AS1 void*)(uintptr_t)g,
                                     (AS3 void*)(unsigned int)(uintptr_t)l,
                                     16, 0, 0);
}

#define Nn 32
#define Tt 64
#define Vv 25
#define NP 51200        // N*T*V positions
#define NBLK 400        // GEMM p-tiles (51200/128)

// ---------------------------------------------------------------------------
// prep: bf16 weight transposes + bias2[w][d] + zero pad
// ---------------------------------------------------------------------------
__global__ __launch_bounds__(256) void prep_kernel(
    const float* __restrict__ Wg, const float* __restrict__ Wt,
    const float* __restrict__ A, const float* __restrict__ bg,
    u16* __restrict__ Wgb, u16* __restrict__ Wtb,
    float* __restrict__ bias2, float* __restrict__ zpad)
{
    const int idx = blockIdx.x * 256 + threadIdx.x;
    const int stride = gridDim.x * 256;
    for (int i = idx; i < 256 * 2304; i += stride) {
        int d = i / 2304, r = i - d * 2304, dt = r >> 8, c = r & 255;
        Wtb[i] = f2bf(Wt[(d * 256 + c) * 9 + dt]);
    }
    for (int i = idx; i < 256 * 768; i += stride) {
        int d = i / 768, r = i - d * 768, k = r >> 8, c = r & 255;
        Wgb[i] = f2bf(Wg[(k * 256 + d) * 256 + c]);
    }
    for (int i = idx; i < 25 * 256; i += stride) {
        int w = i >> 8, d = i & 255;
        float s = 0.f;
        for (int k = 0; k < 3; ++k) {
            float cs = 0.f;
            for (int v = 0; v < 25; ++v) cs += A[(k * 25 + v) * 25 + w];
            s += bg[k * 256 + d] * cs;
        }
        bias2[i] = s;
    }
    for (int i = idx; i < 256; i += stride) zpad[i] = 0.f;
}

// ---------------------------------------------------------------------------
// xa2[p=(n,t,w)][k*256+c] = sum_v x[n,c,t,v] * A[k,v,w]   (bf16 out)
// Thread = c. x-row held in registers; A[k,v,w] is wave-uniform -> s_load
// through constant cache. Inner loop = pure v_fmac_f32 (no per-iter LDS).
// ---------------------------------------------------------------------------
__global__ __launch_bounds__(256) void xa_kernel(
    const float* __restrict__ x, const float* __restrict__ A,
    u16* __restrict__ xa2)
{
    const int t = blockIdx.x, n = blockIdx.y;
    const int tid = threadIdx.x;              // = c
    __shared__ float xs[256 * 25];            // 25.6 KB

    for (int i = tid; i < 6400; i += 256) {   // coalesced stage of x[n,:,t,:]
        int c = i / 25, v = i - c * 25;
        xs[i] = x[((n * 256 + c) * 64 + t) * 25 + v];
    }
    __syncthreads();

    float xr[25];
    #pragma unroll
    for (int v = 0; v < 25; ++v) xr[v] = xs[tid * 25 + v];

    const size_t pbase = ((size_t)n * 64 + t) * 25;
    #pragma unroll 1
    for (int k = 0; k < 3; ++k) {
        float o[25];
        #pragma unroll
        for (int w = 0; w < 25; ++w) {
            float acc = 0.f;
            #pragma unroll
            for (int v = 0; v < 25; ++v)
                acc = fmaf(xr[v], A[(k * 25 + v) * 25 + w], acc);  // uniform -> s_load
            o[w] = acc;
        }
        u16* dst = xa2 + k * 256 + tid;
        #pragma unroll
        for (int w = 0; w < 25; ++w)
            dst[(pbase + w) * 768] = f2bf(o[w]);   // 2B/lane, c-contiguous
    }
}

// ---------------------------------------------------------------------------
// GEMM: C[p][d] = sum_k Ad[p][k] * Bw_rowd[d][k], M-tile 128, N=256, BK=64.
// 8 waves (2M x 4N), per-wave 64x64 out = 4x4 frags of 16x16x32 bf16 MFMA.
// LDS: A 16KB + B 32KB, linear rows of 128B; XOR-swizzle (16B granule) applied
// on the GLOBAL source (stage) and on ds_read addr (both-sides, rule 21).
// TCN=true: Ad rows shift by (dt-4)*25 positions with zero-pad at t edges;
//           epilogue emits bf16 z + per-block BN partials.
// ---------------------------------------------------------------------------
template<int KTOT, bool TCN>
__global__ __launch_bounds__(512, 2) void gemm_kernel(
    const u16* __restrict__ Ad, const u16* __restrict__ Bw,
    const float* __restrict__ bias, u16* __restrict__ outB,
    float* __restrict__ psum, float* __restrict__ psq,
    const u16* __restrict__ zpad)
{
    __shared__ u16 smem[24576];          // 48 KB
    u16* As = smem;                      // [128 rows][64 k] (swizzled)
    u16* Bs = smem + 8192;               // [256 rows][64 k] (swizzled)

    const int tid = threadIdx.x;
    const int wid = tid >> 6, lane = tid & 63;
    const int lr = lane & 15, hk = lane >> 4;
    const int wm = wid >> 2, wn = wid & 3;
    const int blk = blockIdx.x;
    const int rA = lane >> 3, sA = lane & 7;

    v4f acc[4][4];
    const v4f vzero = {0.f, 0.f, 0.f, 0.f};
    #pragma unroll
    for (int mf = 0; mf < 4; ++mf)
        #pragma unroll
        for (int nf = 0; nf < 4; ++nf) acc[mf][nf] = vzero;

    for (int kt = 0; kt < KTOT / 64; ++kt) {
        // ---- stage A: 16 chunks of 1KB (8 rows x 128B); wave does 2 ----
        #pragma unroll
        for (int i = 0; i < 2; ++i) {
            const int ch = wid + i * 8;
            const int row = ch * 8 + rA;
            const int p = blk * 128 + row;
            const int ss = sA ^ (row & 7);          // inverse-swizzled source slot
            const u16* src;
            if (TCN) {
                const int dt = kt >> 2, c0 = (kt & 3) << 6;
                const int tv = p % 1600, t = tv / 25;
                const int tp = t + dt - 4;
                const int p2 = p + (dt - 4) * 25;
                src = ((unsigned)tp < 64u) ? (Ad + (size_t)p2 * 256 + c0 + ss * 8) : zpad;
            } else {
                src = Ad + (size_t)p * 768 + kt * 64 + ss * 8;
            }
            gload_lds16(src, (char*)As + ch * 1024);
        }
        // ---- stage B: 32 chunks; wave does 4 ----
        #pragma unroll
        for (int i = 0; i < 4; ++i) {
            const int ch = wid + i * 8;
            const int d = ch * 8 + rA;
            const int ss = sA ^ (d & 7);
            gload_lds16(Bw + (size_t)d * KTOT + kt * 64 + ss * 8, (char*)Bs + ch * 1024);
        }
        __syncthreads();   // drains vmcnt: staged data visible

        v8s a[4][2], b[4][2];
        #pragma unroll
        for (int mf = 0; mf < 4; ++mf)
            #pragma unroll
            for (int kk = 0; kk < 2; ++kk) {
                const int row = wm * 64 + mf * 16 + lr;
                const int slot = kk * 4 + hk;
                a[mf][kk] = *(const v8s*)((const char*)As + row * 128 + ((slot ^ (row & 7)) << 4));
            }
        #pragma unroll
        for (int nf = 0; nf < 4; ++nf)
            #pragma unroll
            for (int kk = 0; kk < 2; ++kk) {
                const int row = wn * 64 + nf * 16 + lr;
                const int slot = kk * 4 + hk;
                b[nf][kk] = *(const v8s*)((const char*)Bs + row * 128 + ((slot ^ (row & 7)) << 4));
            }
        #pragma unroll
        for (int kk = 0; kk < 2; ++kk)
            #pragma unroll
            for (int mf = 0; mf < 4; ++mf)
                #pragma unroll
                for (int nf = 0; nf < 4; ++nf)
                    acc[mf][nf] = __builtin_amdgcn_mfma_f32_16x16x32_bf16(
                        a[mf][kk], b[nf][kk], acc[mf][nf], 0, 0, 0);
        __syncthreads();   // protect LDS from next stage
    }

    // ---- epilogue ----
    if (!TCN) {
        #pragma unroll
        for (int mf = 0; mf < 4; ++mf) {
            #pragma unroll
            for (int j = 0; j < 4; ++j) {
                const int p = blk * 128 + wm * 64 + mf * 16 + hk * 4 + j;
                const int w = p % 25;
                #pragma unroll
                for (int nf = 0; nf < 4; ++nf) {
                    const int d = wn * 64 + nf * 16 + lr;
                    outB[(size_t)p * 256 + d] = f2bf(acc[mf][nf][j] + bias[w * 256 + d]);
                }
            }
        }
    } else {
        float s[4], q[4];
        #pragma unroll
        for (int nf = 0; nf < 4; ++nf) {
            const int d = wn * 64 + nf * 16 + lr;
            const float bb = bias[d];
            s[nf] = 0.f; q[nf] = 0.f;
            #pragma unroll
            for (int mf = 0; mf < 4; ++mf) {
                #pragma unroll
                for (int j = 0; j < 4; ++j) {
                    const int p = blk * 128 + wm * 64 + mf * 16 + hk * 4 + j;
                    const float zz = acc[mf][nf][j] + bb;
                    outB[(size_t)p * 256 + d] = f2bf(zz);
                    s[nf] += zz; q[nf] += zz * zz;
                }
            }
            s[nf] += __shfl_xor(s[nf], 16); s[nf] += __shfl_xor(s[nf], 32);
            q[nf] += __shfl_xor(q[nf], 16); q[nf] += __shfl_xor(q[nf], 32);
        }
        __syncthreads();
        float* red = (float*)smem;     // [2][256] sums, [2][256] sq
        if (hk == 0) {
            #pragma unroll
            for (int nf = 0; nf < 4; ++nf) {
                const int d = wn * 64 + nf * 16 + lr;
                red[wm * 256 + d] = s[nf];
                red[512 + wm * 256 + d] = q[nf];
            }
        }
        __syncthreads();
        if (tid < 256) {
            psum[(size_t)tid * NBLK + blk] = red[tid] + red[256 + tid];
            psq[(size_t)tid * NBLK + blk]  = red[512 + tid] + red[768 + tid];
        }
    }
}

// ---------------------------------------------------------------------------
// BN stats: reduce 400 block-partials per channel -> scale/shift
// ---------------------------------------------------------------------------
__global__ __launch_bounds__(256) void bn_stats_kernel(
    const float* __restrict__ psum, const float* __restrict__ psq,
    const float* __restrict__ gamma, const float* __restrict__ beta,
    float* __restrict__ scale, float* __restrict__ shift)
{
    const int d = blockIdx.x, tid = threadIdx.x;
    float s = 0.f, q = 0.f;
    for (int i = tid; i < NBLK; i += 256) {
        s += psum[(size_t)d * NBLK + i];
        q += psq[(size_t)d * NBLK + i];
    }
    #pragma unroll
    for (int off = 32; off; off >>= 1) {
        s += __shfl_down(s, off);
        q += __shfl_down(q, off);
    }
    __shared__ float rs[4], rq[4];
    if ((tid & 63) == 0) { rs[tid >> 6] = s; rq[tid >> 6] = q; }
    __syncthreads();
    if (tid == 0) {
        s = rs[0] + rs[1] + rs[2] + rs[3];
        q = rq[0] + rq[1] + rq[2] + rq[3];
        const float mean = s / 51200.f;
        const float var = q / 51200.f - mean * mean;
        const float inv = rsqrtf(var + 1e-5f);
        scale[d] = gamma[d] * inv;
        shift[d] = beta[d] - gamma[d] * inv * mean;
    }
}

// ---------------------------------------------------------------------------
// out[n,d,tv] = relu(z[p][d]*scale[d]+shift[d] + x[n,d,tv]); LDS transpose.
// ---------------------------------------------------------------------------
__global__ __launch_bounds__(256) void bn_apply_kernel(
    const u16* __restrict__ zb, const float* __restrict__ x,
    const float* __restrict__ scale, const float* __restrict__ shift,
    float* __restrict__ out)
{
    const int chunk = blockIdx.x;   // 0..24
    const int n = blockIdx.y;       // 0..31
    const int tid = threadIdx.x;
    __shared__ u16 zs[128 * 66];    // 16.9 KB, padded rows
    const size_t p0 = (size_t)n * 1600 + chunk * 64;

    for (int half = 0; half < 2; ++half) {
        const int d0 = half * 128;
        if (half) __syncthreads();
        for (int i = tid; i < 128 * 64; i += 256) {
            const int pl = i >> 7, dl = i & 127;
            zs[dl * 66 + pl] = zb[(p0 + pl) * 256 + d0 + dl];
        }
        __syncthreads();
        for (int i = tid; i < 128 * 64; i += 256) {
            const int dl = i >> 6, j = i & 63;
            const int d = d0 + dl;
            const size_t addr = ((size_t)n * 256 + d) * 1600 + chunk * 64 + j;
            const float r = bf2f(zs[dl * 66 + j]) * scale[d] + shift[d] + x[addr];
            out[addr] = fmaxf(r, 0.f);
        }
    }
}

extern "C" void kernel_launch(void* const* d_in, const int* in_sizes, int n_in,
                              void* d_out, int out_size, void* d_ws, size_t ws_size,
                              hipStream_t stream)
{
    const float* x     = (const float*)d_in[0];
    const float* A     = (const float*)d_in[1];
    const float* Wg    = (const float*)d_in[2];
    const float* bg    = (const float*)d_in[3];
    const float* Wt    = (const float*)d_in[4];
    const float* bt    = (const float*)d_in[5];
    const float* gamma = (const float*)d_in[6];
    const float* beta  = (const float*)d_in[7];
    float* out = (float*)d_out;

    char* w = (char*)d_ws;
    u16*   xa2   = (u16*)(w);                    // 78,643,200 B
    u16*   y2T   = (u16*)(w + 78643200);         // 26,214,400 B
    u16*   zb    = (u16*)(w + 104857600);        // 26,214,400 B
    u16*   Wgb   = (u16*)(w + 131072000);        //    393,216 B
    u16*   Wtb   = (u16*)(w + 131465216);        //  1,179,648 B
    float* bias2 = (float*)(w + 132644864);      //     25,600 B
    float* psum  = (float*)(w + 132670464);      //    409,600 B
    float* psq   = (float*)(w + 133080064);      //    409,600 B
    float* scale = (float*)(w + 133489664);      //      1,024 B
    float* shift = (float*)(w + 133490688);      //      1,024 B
    float* zpad  = (float*)(w + 133491712);      //      1,024 B (zeroed)

    prep_kernel<<<512, 256, 0, stream>>>(Wg, Wt, A, bg, Wgb, Wtb, bias2, zpad);
    xa_kernel<<<dim3(64, 32), 256, 0, stream>>>(x, A, xa2);
    gemm_kernel<768, false><<<NBLK, 512, 0, stream>>>(xa2, Wgb, bias2, y2T,
                                                      nullptr, nullptr, (const u16*)zpad);
    gemm_kernel<2304, true><<<NBLK, 512, 0, stream>>>(y2T, Wtb, bt, zb,
                                                      psum, psq, (const u16*)zpad);
    bn_stats_kernel<<<256, 256, 0, stream>>>(psum, psq, gamma, beta, scale, shift);
    bn_apply_kernel<<<dim3(25, 32), 256, 0, stream>>>(zb, x, scale, shift, out);
}